// Round 5
// baseline (3021.172 us; speedup 1.0000x reference)
//
#include <hip/hip_runtime.h>
#include <stdint.h>

#define BN_ 2
#define NPT 16384
#define MPT 8192
#define NROI 128
#define KP 2048
#define WV2 4          // waves in k_fps (1 per SIMD)

typedef unsigned long long u64;
typedef unsigned u32;

// ---- workspace layout (float offsets) ----
#define FEATS_LEN (4096*352)
#define CNTR_OFF  (FEATS_LEN)
#define CNTC_OFF  (CNTR_OFF + 4096)
#define FRAW_OFF  (CNTC_OFF + 4096)
#define FRAW_LEN  (BN_*NPT*32)
#define GC3_OFF   (FRAW_OFF + FRAW_LEN)
#define GC3_LEN   (BN_*MPT*64)
#define FLAGS_F_OFF (GC3_OFF + GC3_LEN)
#define CX_OFF    (FLAGS_F_OFF + (BN_*NPT)/4)
#define CY_OFF    (CX_OFF + BN_*NPT)
#define CZ_OFF    (CY_OFF + BN_*NPT)
#define SOID_OFF  (CZ_OFF + BN_*NPT)
#define VV_OFF    (SOID_OFF + BN_*NPT)
#define OUT_KP_OFF (4096*128)

// ---------------- helpers ----------------
__device__ __forceinline__ u32 ordf(float f) {
    u32 b = __float_as_uint(f);
    return b ^ ((u32)(((int)b) >> 31) | 0x80000000u);
}
__device__ __forceinline__ float deord(u32 v) {
    u32 b = (v & 0x80000000u) ? (v ^ 0x80000000u) : ~v;
    return __uint_as_float(b);
}
template <int CTRL>
__device__ __forceinline__ u32 dppmov(u32 v) {
    return (u32)__builtin_amdgcn_update_dpp((int)v, (int)v, CTRL, 0xF, 0xF, false);
}
__device__ __forceinline__ u32 wave_umax_dpp(u32 v) {
#define STG(C) { u32 o = dppmov<C>(v); v = (o > v) ? o : v; }
    STG(0x111) STG(0x112) STG(0x114) STG(0x118) STG(0x142) STG(0x143)
#undef STG
    return (u32)__builtin_amdgcn_readlane((int)v, 63);
}
__device__ __forceinline__ float wave_fmin(float v) {
#define STG(C) { float o = __uint_as_float(dppmov<C>(__float_as_uint(v))); v = fminf(v, o); }
    STG(0x111) STG(0x112) STG(0x114) STG(0x118) STG(0x142) STG(0x143)
#undef STG
    return __uint_as_float((u32)__builtin_amdgcn_readlane((int)__float_as_uint(v), 63));
}
__device__ __forceinline__ float wave_fmax(float v) {
#define STG(C) { float o = __uint_as_float(dppmov<C>(__float_as_uint(v))); v = fmaxf(v, o); }
    STG(0x111) STG(0x112) STG(0x114) STG(0x118) STG(0x142) STG(0x143)
#undef STG
    return __uint_as_float((u32)__builtin_amdgcn_readlane((int)__float_as_uint(v), 63));
}
// quad_perm reduce stage carrying (keyHi,keyLo,x,y,z)
template <int CTRL>
__device__ __forceinline__ void quadstage(u32& hi, u32& lo, float& x, float& y, float& z) {
    u32 nh = dppmov<CTRL>(hi), nl = dppmov<CTRL>(lo);
    u32 nx = dppmov<CTRL>(__float_as_uint(x));
    u32 ny = dppmov<CTRL>(__float_as_uint(y));
    u32 nz = dppmov<CTRL>(__float_as_uint(z));
    bool g = (nh > hi) || (nh == hi && nl > lo);
    hi = g ? nh : hi; lo = g ? nl : lo;
    x = g ? __uint_as_float(nx) : x;
    y = g ? __uint_as_float(ny) : y;
    z = g ? __uint_as_float(nz) : z;
}
__device__ __forceinline__ u32 part4(u32 v) {
    v = (v | (v << 2)) & 0x33u; v = (v | (v << 1)) & 0x55u; return v;
}

// ---------------- K1: ROI validity flags (bit-exact vs reference) ----------------
__global__ void k_flags(const float* __restrict__ pts, const float* __restrict__ bbox,
                        unsigned char* __restrict__ flags) {
#pragma clang fp contract(off)
    __shared__ float rx[NROI], ry[NROI], rz[NROI], rt[NROI];
    int b = blockIdx.x >> 6;
    int t = threadIdx.x;
    if (t < NROI) {
        const float* rr = bbox + (size_t)(b * NROI + t) * 7;
        rx[t] = rr[0]; ry[t] = rr[1]; rz[t] = rr[2];
        float hx = rr[3] * 0.5f, hy = rr[4] * 0.5f, hz = rr[5] * 0.5f;
        rt[t] = sqrtf(((hx * hx) + (hy * hy)) + (hz * hz)) + 2.4f;
    }
    __syncthreads();
    int p = (blockIdx.x & 63) * 256 + t;
    const float* pr = pts + (size_t)(b * NPT + p) * 5;
    float x = pr[0], y = pr[1], z = pr[2];
    float mind = 3.4e38f, th = 0.f;
    for (int r = 0; r < NROI; ++r) {
        float dx = x - rx[r], dy = y - ry[r], dz = z - rz[r];
        float ds = sqrtf(((dx * dx) + (dy * dy)) + (dz * dz));
        if (ds < mind) { mind = ds; th = rt[r]; }
    }
    flags[b * NPT + p] = (mind < th) ? 1 : 0;
}

// ---------------- K2a: Morton counting-sort of valid points ----------------
__global__ void __launch_bounds__(512, 1)
k_sort(const float* __restrict__ pts, const unsigned char* __restrict__ flags,
       float* __restrict__ sxg, float* __restrict__ syg, float* __restrict__ szg,
       int* __restrict__ soidg, int* __restrict__ vg) {
    __shared__ int hist[256];
    __shared__ int wsum[8];
    int b = blockIdx.x, t = threadIdx.x, lane = t & 63, w = t >> 6;
    const float* pbase = pts + (size_t)b * NPT * 5;
    const unsigned char* fb = flags + b * NPT;
    float* SX = sxg + (size_t)b * NPT;
    float* SY = syg + (size_t)b * NPT;
    float* SZ = szg + (size_t)b * NPT;
    int*   SO = soidg + (size_t)b * NPT;

    for (int i = t; i < 256; i += 512) hist[i] = 0;
    __syncthreads();

    int chunk = t * 32;
    u32 fl = 0, cells[8];
#pragma unroll
    for (int i = 0; i < 8; ++i) cells[i] = 0;
    int cnt = 0;
    for (int j = 0; j < 32; ++j) {
        if (fb[chunk + j]) {
            const float* pr = pbase + (size_t)(chunk + j) * 5;
            float x = pr[0], y = pr[1];
            int cxi = (int)fmaxf(0.f, fminf(15.f, (x + 75.2f) * (16.0f / 150.4f)));
            int cyi = (int)fmaxf(0.f, fminf(15.f, (y + 75.2f) * (16.0f / 150.4f)));
            u32 cell = part4((u32)cxi) | (part4((u32)cyi) << 1);
            atomicAdd(&hist[cell], 1);
            cells[j >> 2] |= cell << ((j & 3) * 8);
            fl |= 1u << j;
            ++cnt;
        }
    }
    int s = cnt;
#pragma unroll
    for (int m = 1; m < 64; m <<= 1) s += __shfl_xor(s, m, 64);
    if (lane == 0) wsum[w] = s;
    __syncthreads();
    int V = 0;
    for (int i = 0; i < 8; ++i) V += wsum[i];
    if (t == 0) vg[b] = V;
    __syncthreads();

    // exclusive scan of 256 bins
    int v = (t < 256) ? hist[t] : 0;
    int incl = v;
#pragma unroll
    for (int off = 1; off < 64; off <<= 1) {
        int u = __shfl_up(incl, off, 64);
        if (lane >= off) incl += u;
    }
    if (lane == 63) wsum[w] = incl;
    __syncthreads();
    if (t < 256) {
        int off = 0;
        for (int i = 0; i < w; ++i) off += wsum[i];
        hist[t] = off + incl - v;
    }
    __syncthreads();

    for (int j = 0; j < 32; ++j) {
        if ((fl >> j) & 1u) {
            u32 cell = (cells[j >> 2] >> ((j & 3) * 8)) & 0xFFu;
            int pos = atomicAdd(&hist[cell], 1);
            const float* pr = pbase + (size_t)(chunk + j) * 5;
            SX[pos] = pr[0]; SY[pos] = pr[1]; SZ[pos] = pr[2];
            SO[pos] = chunk + j;
        }
    }
}

// ---------------- FPS core: column-pruned, write-only candidates, LDS kp buffer ----
template <int NS>
__device__ void fps_core(int t, int lane, int w, int V,
                         const float* __restrict__ SX, const float* __restrict__ SY,
                         const float* __restrict__ SZ, const int* __restrict__ SO,
                         u32* cand, float* kbuf, float* __restrict__ kout) {
#pragma clang fp contract(off)
    float px[NS], py[NS], pz[NS], d[NS];
    u32 inv[NS];
    const int wbase = w * 64 * NS;
#pragma unroll
    for (int j = 0; j < NS; ++j) {
        int sid = wbase + j * 64 + lane;
        bool in = sid < V;
        px[j] = in ? SX[sid] : 3e38f;
        py[j] = in ? SY[sid] : 3e38f;
        pz[j] = in ? SZ[sid] : 3e38f;
        d[j]  = in ? 1e10f : -3.0e38f;
        inv[j] = in ? ~(u32)SO[sid] : 0u;
    }
    // column AABBs: lane j holds column j's box (column = 64 consecutive sorted pts)
    float cLx = 3e38f, cLy = 3e38f, cLz = 3e38f;
    float cHx = -3e38f, cHy = -3e38f, cHz = -3e38f;
#pragma unroll
    for (int j = 0; j < NS; ++j) {
        bool in = (wbase + j * 64 + lane) < V;
        float mnx = wave_fmin(px[j]);
        float mny = wave_fmin(py[j]);
        float mnz = wave_fmin(pz[j]);
        float mxx = wave_fmax(in ? px[j] : -3e38f);
        float mxy = wave_fmax(in ? py[j] : -3e38f);
        float mxz = wave_fmax(in ? pz[j] : -3e38f);
        if (lane == j) { cLx = mnx; cLy = mny; cLz = mnz; cHx = mxx; cHy = mxy; cHz = mxz; }
    }

    // prime candidate: (ordf(d), ~origID) lexicographic max + its xyz
    u32 bHi = 0, bLo = 0; float bx_ = 0.f, by_ = 0.f, bz_ = 0.f;
#pragma unroll
    for (int j = 0; j < NS; ++j) {
        u32 oj = ordf(d[j]);
        bool g = (oj > bHi) || (oj == bHi && inv[j] > bLo);
        bHi = g ? oj : bHi; bLo = g ? inv[j] : bLo;
        bx_ = g ? px[j] : bx_; by_ = g ? py[j] : by_; bz_ = g ? pz[j] : bz_;
    }
    u32 maxOrd = wave_umax_dpp(bHi);
    u32 myI = (bHi == maxOrd) ? bLo : 0u;
    u32 maxInv = wave_umax_dpp(myI);
    bool havC = (bHi == maxOrd) && (bLo == maxInv);
    float bd = deord(maxOrd);
    {
        u32* cb = cand + w * 8;   // buffer 0
        if (havC) {
            cb[0] = maxOrd; cb[1] = maxInv;
            cb[2] = __float_as_uint(bx_); cb[3] = __float_as_uint(by_); cb[4] = __float_as_uint(bz_);
        }
    }
    __syncthreads();

    for (int k = 0; k < KP; ++k) {
        int p = k & 1;
        // lane-parallel candidate fetch: lane q=lane&3 reads wave-q candidate
        const u32* cb = cand + ((p << 2) + (lane & 3)) * 8;
        u32 fhi = cb[0], flo = cb[1];
        float fx = __uint_as_float(cb[2]);
        float fy = __uint_as_float(cb[3]);
        float fz = __uint_as_float(cb[4]);
        quadstage<0xB1>(fhi, flo, fx, fy, fz);   // [1,0,3,2]
        quadstage<0x4E>(fhi, flo, fx, fy, fz);   // [2,3,0,1]
        float bx = fx, by = fy, bz = fz;
        if (t == 0) { kbuf[k * 3] = bx; kbuf[k * 3 + 1] = by; kbuf[k * 3 + 2] = bz; }

        // per-column exact prune mask (lane l evaluates column l's AABB)
        float ddx = fmaxf(0.f, fmaxf(cLx - bx, bx - cHx));
        float ddy = fmaxf(0.f, fmaxf(cLy - by, by - cHy));
        float ddz = fmaxf(0.f, fmaxf(cLz - bz, bz - cHz));
        float ad2 = (ddx * ddx + ddy * ddy) + ddz * ddz;
        bool colAct = !(ad2 > bd * 1.00002f + 1e-6f);
        u64 mask = __ballot(colAct);

        if (mask) {
            bHi = 0; bLo = 0;
#pragma unroll
            for (int j = 0; j < NS; ++j) {
                if (mask & (1ull << j)) {
                    float dx = px[j] - bx, dy = py[j] - by, dz = pz[j] - bz;
                    float nd = ((dx * dx) + (dy * dy)) + dz * dz;
                    d[j] = fminf(d[j], nd);
                }
                u32 oj = ordf(d[j]);
                bool g = (oj > bHi) || (oj == bHi && inv[j] > bLo);
                bHi = g ? oj : bHi; bLo = g ? inv[j] : bLo;
                bx_ = g ? px[j] : bx_; by_ = g ? py[j] : by_; bz_ = g ? pz[j] : bz_;
            }
            maxOrd = wave_umax_dpp(bHi);
            myI = (bHi == maxOrd) ? bLo : 0u;
            maxInv = wave_umax_dpp(myI);
            havC = (bHi == maxOrd) && (bLo == maxInv);
            bd = deord(maxOrd);
        }
        // write-only publication of (possibly unchanged) candidate for next step
        u32* wb = cand + (((p ^ 1) << 2) + w) * 8;
        if (havC) {
            wb[0] = maxOrd; wb[1] = maxInv;
            wb[2] = __float_as_uint(bx_); wb[3] = __float_as_uint(by_); wb[4] = __float_as_uint(bz_);
        }
        __syncthreads();
    }
    // flush keypoints LDS -> global (coalesced)
    for (int i = t; i < KP * 3; i += 256) kout[i] = kbuf[i];
}

// ---------------- K2b: exact FPS ----------------
__global__ void __launch_bounds__(256, 1)
k_fps(const float* __restrict__ pts,
      const float* __restrict__ sxg, const float* __restrict__ syg,
      const float* __restrict__ szg, const int* __restrict__ soidg,
      const int* __restrict__ vg, float* __restrict__ kpOut) {
#pragma clang fp contract(off)
    __shared__ __align__(16) u32 cand[2 * WV2 * 8];
    __shared__ float kbuf[KP * 3];
    int b = blockIdx.x, t = threadIdx.x, lane = t & 63, w = t >> 6;
    int V = vg[b];
    const float* SX = sxg + (size_t)b * NPT;
    const float* SY = syg + (size_t)b * NPT;
    const float* SZ = szg + (size_t)b * NPT;
    const int*   SO = soidg + (size_t)b * NPT;
    float* kout = kpOut + (size_t)b * KP * 3;
    if (V == 0) {
        const float* pb = pts + (size_t)b * NPT * 5;
        if (t == 0)
            for (int k = 0; k < KP; ++k) {
                kout[k * 3] = pb[0]; kout[k * 3 + 1] = pb[1]; kout[k * 3 + 2] = pb[2];
            }
        return;
    }
    int nsw = (V + 255) >> 8;
    if (nsw <= 12)      fps_core<12>(t, lane, w, V, SX, SY, SZ, SO, cand, kbuf, kout);
    else if (nsw <= 16) fps_core<16>(t, lane, w, V, SX, SY, SZ, SO, cand, kbuf, kout);
    else if (nsw <= 20) fps_core<20>(t, lane, w, V, SX, SY, SZ, SO, cand, kbuf, kout);
    else if (nsw <= 24) fps_core<24>(t, lane, w, V, SX, SY, SZ, SO, cand, kbuf, kout);
    else if (nsw <= 28) fps_core<28>(t, lane, w, V, SX, SY, SZ, SO, cand, kbuf, kout);
    else                fps_core<32>(t, lane, w, V, SX, SY, SZ, SO, cand, kbuf, kout);
}

// ---------------- K3: bilinear BEV sampling ----------------
__global__ void k_bilinear(const float* __restrict__ sf, const float* __restrict__ kp,
                           float* __restrict__ feats) {
    int bid = blockIdx.x;
    int b = bid >> 11, kk = bid & 2047;
    int c = threadIdx.x;
    const float* kpr = kp + (size_t)(b * KP + kk) * 3;
    float x = kpr[0], y = kpr[1];
    float xi = ((x - (-75.2f)) / 0.1f) / 8.0f;
    float yi = ((y - (-75.2f)) / 0.1f) / 8.0f;
    int x0 = (int)floorf(xi); x0 = min(max(x0, 0), 187);
    int x1 = min(max(x0 + 1, 0), 187);
    int y0 = (int)floorf(yi); y0 = min(max(y0, 0), 187);
    int y1 = min(max(y0 + 1, 0), 187);
    float xf0 = (float)x0, xf1 = (float)x1, yf0 = (float)y0, yf1 = (float)y1;
    float wa = (xf1 - xi) * (yf1 - yi), wb = (xf1 - xi) * (yi - yf0);
    float wc = (xi - xf0) * (yf1 - yi), wd = (xi - xf0) * (yi - yf0);
    const float* plane = sf + (size_t)(b * 256 + c) * 188 * 188;
    float Ia = plane[y0 * 188 + x0], Ib = plane[y1 * 188 + x0];
    float Ic = plane[y0 * 188 + x1], Id = plane[y1 * 188 + x1];
    feats[(size_t)(b * KP + kk) * 352 + c] = Ia * wa + Ib * wb + Ic * wc + Id * wd;
}

// ---------------- K4a: raw point feature MLP ----------------
__global__ void k_fraw(const float* __restrict__ pts, const float* __restrict__ Wr,
                       const float* __restrict__ br, float* __restrict__ fraw) {
    int idx = blockIdx.x * 256 + threadIdx.x;
    int c = idx & 31, n = idx >> 5;
    const float* pr = pts + (size_t)n * 5;
    float v = pr[3] * Wr[c] + pr[4] * Wr[32 + c] + br[c];
    fraw[(size_t)n * 32 + c] = fmaxf(v, 0.f);
}

// ---------------- K4b: conv3 point feature MLP ----------------
__global__ void k_gc3(const float* __restrict__ conv3, const float* __restrict__ Wc,
                      const float* __restrict__ bc, float* __restrict__ gc3) {
    __shared__ float w[4096];
    __shared__ float rf[4][64];
    int t = threadIdx.x;
    for (int i = t; i < 4096; i += 256) w[i] = Wc[i];
    int r = blockIdx.x * 4 + (t >> 6);
    int c = t & 63;
    rf[t >> 6][c] = conv3[(size_t)r * 67 + 3 + c];
    __syncthreads();
    float s = bc[c];
#pragma unroll 8
    for (int k = 0; k < 64; ++k) s = fmaf(rf[t >> 6][k], w[k * 64 + c], s);
    gc3[(size_t)r * 64 + c] = fmaxf(s, 0.f);
}

// ---------------- K5: raw radius aggregation ----------------
__global__ void k_rawagg(const float* __restrict__ pts, const float* __restrict__ kp,
                         const float* __restrict__ fraw, float* __restrict__ feats,
                         float* __restrict__ cntR) {
    __shared__ float sp[2560];
    int bid = blockIdx.x;
    int b = bid >> 7, kb = (bid >> 4) & 7, s = bid & 15;
    int t = threadIdx.x;
    int kk = kb * 256 + t, row = b * KP + kk;
    float kx = kp[row * 3], ky = kp[row * 3 + 1], kz = kp[row * 3 + 2];
    float acc[32];
#pragma unroll
    for (int c = 0; c < 32; ++c) acc[c] = 0.f;
    float cnt = 0.f;
    const float R2 = 0.8f * 0.8f;
    for (int tile = 0; tile < 2; ++tile) {
        int nbase = s * 1024 + tile * 512;
        const float* src = pts + (size_t)(b * NPT + nbase) * 5;
        for (int i = t; i < 2560; i += 256) sp[i] = src[i];
        __syncthreads();
        for (int j = 0; j < 512; ++j) {
            float dx = kx - sp[j * 5], dy = ky - sp[j * 5 + 1], dz = kz - sp[j * 5 + 2];
            float d2 = fmaf(dx, dx, fmaf(dy, dy, dz * dz));
            if (d2 < R2) {
                cnt += 1.f;
                const float* fp = fraw + (size_t)(b * NPT + nbase + j) * 32;
#pragma unroll
                for (int c = 0; c < 32; ++c) acc[c] += fp[c];
            }
        }
        __syncthreads();
    }
    float* dst = feats + (size_t)row * 352 + 256;
#pragma unroll
    for (int c = 0; c < 32; ++c) if (acc[c] != 0.f) atomicAdd(dst + c, acc[c]);
    if (cnt != 0.f) atomicAdd(cntR + row, cnt);
}

// ---------------- K6: conv3 radius aggregation ----------------
__global__ void k_c3agg(const float* __restrict__ conv3, const float* __restrict__ kp,
                        const float* __restrict__ gc3, float* __restrict__ feats,
                        float* __restrict__ cntC) {
    __shared__ float sq[256 * 3];
    int bid = blockIdx.x;
    int b = bid >> 7, kb = (bid >> 4) & 7, s = bid & 15;
    int t = threadIdx.x;
    int kk = kb * 256 + t, row = b * KP + kk;
    float kx = kp[row * 3], ky = kp[row * 3 + 1], kz = kp[row * 3 + 2];
    float acc[64];
#pragma unroll
    for (int c = 0; c < 64; ++c) acc[c] = 0.f;
    float cnt = 0.f;
    const float R2 = 1.6f * 1.6f;
    for (int tile = 0; tile < 2; ++tile) {
        int nbase = s * 512 + tile * 256;
        const float* src = conv3 + (size_t)(b * MPT + nbase + t) * 67;
        sq[t * 3] = src[0]; sq[t * 3 + 1] = src[1]; sq[t * 3 + 2] = src[2];
        __syncthreads();
        for (int j = 0; j < 256; ++j) {
            float dx = kx - sq[j * 3], dy = ky - sq[j * 3 + 1], dz = kz - sq[j * 3 + 2];
            float d2 = fmaf(dx, dx, fmaf(dy, dy, dz * dz));
            if (d2 < R2) {
                cnt += 1.f;
                const float* gp = gc3 + (size_t)(b * MPT + nbase + j) * 64;
#pragma unroll
                for (int c = 0; c < 64; ++c) acc[c] += gp[c];
            }
        }
        __syncthreads();
    }
    float* dst = feats + (size_t)row * 352 + 288;
#pragma unroll
    for (int c = 0; c < 64; ++c) if (acc[c] != 0.f) atomicAdd(dst + c, acc[c]);
    if (cnt != 0.f) atomicAdd(cntC + row, cnt);
}

// ---------------- K7: fuse GEMM + BN + ReLU ----------------
__global__ void k_fuse(const float* __restrict__ feats, const float* __restrict__ cntR,
                       const float* __restrict__ cntC, const float* __restrict__ Wf,
                       const float* __restrict__ gma, const float* __restrict__ bta,
                       const float* __restrict__ mean, const float* __restrict__ var,
                       float* __restrict__ out) {
    __shared__ float a[2][352];
    int r0 = blockIdx.x * 2;
    int t = threadIdx.x;
    for (int i = t; i < 704; i += 256) {
        int rr = i >= 352 ? 1 : 0;
        int k = i - rr * 352;
        float v = feats[(size_t)(r0 + rr) * 352 + k];
        if (k >= 256) {
            float cn = (k < 288) ? cntR[r0 + rr] : cntC[r0 + rr];
            v = v / fmaxf(cn, 1.0f);
        }
        a[rr][k] = v;
    }
    __syncthreads();
    int r = t >> 7, c = t & 127;
    float s = 0.f;
#pragma unroll 4
    for (int k = 0; k < 352; ++k) s = fmaf(a[r][k], Wf[k * 128 + c], s);
    s = (s - mean[c]) * (1.0f / sqrtf(var[c] + 1e-5f)) * gma[c] + bta[c];
    out[(size_t)(r0 + r) * 128 + c] = fmaxf(s, 0.f);
}

// ---------------- launch ----------------
extern "C" void kernel_launch(void* const* d_in, const int* in_sizes, int n_in,
                              void* d_out, int out_size, void* d_ws, size_t ws_size,
                              hipStream_t stream) {
    const float* pts   = (const float*)d_in[0];
    const float* bbox  = (const float*)d_in[1];
    const float* sf    = (const float*)d_in[2];
    const float* conv3 = (const float*)d_in[3];
    const float* Wraw  = (const float*)d_in[4];
    const float* braw  = (const float*)d_in[5];
    const float* Wc3   = (const float*)d_in[6];
    const float* bc3   = (const float*)d_in[7];
    const float* Wf    = (const float*)d_in[8];
    const float* gma   = (const float*)d_in[9];
    const float* bta   = (const float*)d_in[10];
    const float* mean  = (const float*)d_in[11];
    const float* var   = (const float*)d_in[12];

    float* wsf   = (float*)d_ws;
    float* feats = wsf;
    float* cntR  = wsf + CNTR_OFF;
    float* cntC  = wsf + CNTC_OFF;
    float* fraw  = wsf + FRAW_OFF;
    float* gc3   = wsf + GC3_OFF;
    unsigned char* flags = (unsigned char*)(wsf + FLAGS_F_OFF);
    float* sxg   = wsf + CX_OFF;
    float* syg   = wsf + CY_OFF;
    float* szg   = wsf + CZ_OFF;
    int*   soidg = (int*)(wsf + SOID_OFF);
    int*   vg    = (int*)(wsf + VV_OFF);

    float* outp  = (float*)d_out;
    float* kpOut = outp + OUT_KP_OFF;

    hipMemsetAsync(d_ws, 0, (size_t)(FEATS_LEN + 8192) * 4, stream);

    k_flags<<<BN_ * 64, 256, 0, stream>>>(pts, bbox, flags);
    k_sort<<<BN_, 512, 0, stream>>>(pts, flags, sxg, syg, szg, soidg, vg);
    k_fps<<<BN_, 256, 0, stream>>>(pts, sxg, syg, szg, soidg, vg, kpOut);
    k_bilinear<<<BN_ * KP, 256, 0, stream>>>(sf, kpOut, feats);
    k_fraw<<<(BN_ * NPT * 32) / 256, 256, 0, stream>>>(pts, Wraw, braw, fraw);
    k_gc3<<<(BN_ * MPT) / 4, 256, 0, stream>>>(conv3, Wc3, bc3, gc3);
    k_rawagg<<<BN_ * 128, 256, 0, stream>>>(pts, kpOut, fraw, feats, cntR);
    k_c3agg<<<BN_ * 128, 256, 0, stream>>>(conv3, kpOut, gc3, feats, cntC);
    k_fuse<<<2048, 256, 0, stream>>>(feats, cntR, cntC, Wf, gma, bta, mean, var, outp);
}